// Round 3
// baseline (266.636 us; speedup 1.0000x reference)
//
#include <hip/hip_runtime.h>
#include <hip/hip_bf16.h>
#include <cstdint>

#define TB 8
#define TN 1024
#define TC 768
#define TH 12
#define THD 64
#define TM (TB*TN)          // 8192 rows
#define TNQKV (3*TC)        // 2304
// SCALE * log2(e) = 0.125 * 1.4426950408889634
#define QSCALE_LOG2E 0.18033688011112042f
// defer-max threshold: 8 nats in log2 units
#define THR_BITS 11.541560327111708f

typedef __attribute__((ext_vector_type(8))) short s16x8;
typedef __attribute__((ext_vector_type(4))) short s16x4;
typedef __attribute__((ext_vector_type(4))) float f32x4;

__device__ __forceinline__ unsigned short f2bf(float f) {
    union { float f; unsigned int u; } v; v.f = f;
    unsigned int u = v.u;
    return (unsigned short)((u + 0x7FFFu + ((u >> 16) & 1u)) >> 16);
}

__device__ __forceinline__ float bf2f(unsigned short h) {
    union { float f; unsigned int u; } v; v.u = ((unsigned int)h) << 16;
    return v.f;
}

__device__ __forceinline__ void gload_lds16(const unsigned short* g, unsigned short* l) {
    __builtin_amdgcn_global_load_lds(
        (const __attribute__((address_space(1))) unsigned int*)g,
        (__attribute__((address_space(3))) unsigned int*)l,
        16, 0, 0);
}

// ---------------- f32 -> bf16 conversion (vectorized, memory-bound) ----------
__global__ __launch_bounds__(256) void cvt_kernel(const float* __restrict__ in,
                                                  unsigned short* __restrict__ out,
                                                  int n8) {
    int i = blockIdx.x * blockDim.x + threadIdx.x;
    if (i >= n8) return;
    f32x4 a = *(const f32x4*)(in + (size_t)i * 8);
    f32x4 b = *(const f32x4*)(in + (size_t)i * 8 + 4);
    s16x8 r;
    #pragma unroll
    for (int e = 0; e < 4; e++) r[e] = (short)f2bf(a[e]);
    #pragma unroll
    for (int e = 0; e < 4; e++) r[4 + e] = (short)f2bf(b[e]);
    *(s16x8*)(out + (size_t)i * 8) = r;
}

// ---------------- bf16 GEMM, C = A * B^T (+bias). m97-style 128x128 tile -----
template<bool BIAS, bool OBF16>
__global__ __launch_bounds__(256) void gemm_bt(
    const unsigned short* __restrict__ A,
    const unsigned short* __restrict__ Bm,
    void* __restrict__ Cout,
    const float* __restrict__ bias,
    int M, int Nn, int K)
{
    __shared__ unsigned short As[128 * 32];
    __shared__ unsigned short Bs[128 * 32];
    const int t = threadIdx.x;
    const int w = t >> 6, l = t & 63;
    const int lr = l & 15, lh = l >> 4;
    const int wm = w >> 1, wn = w & 1;     // 2x2 wave grid, 64x64 out per wave
    const int bm = blockIdx.x, bn = blockIdx.y;

    f32x4 acc[4][4] = {};

    const unsigned short* Ab = A + (size_t)bm * 128 * K;
    const unsigned short* Bb = Bm + (size_t)bn * 128 * K;

    for (int kt = 0; kt < K; kt += 32) {
        __syncthreads();
        {
            const int c0 = t, c1 = t + 256;
            gload_lds16(Ab + (size_t)(c0 >> 2) * K + kt + (c0 & 3) * 8, As + c0 * 8);
            gload_lds16(Ab + (size_t)(c1 >> 2) * K + kt + (c1 & 3) * 8, As + c1 * 8);
            gload_lds16(Bb + (size_t)(c0 >> 2) * K + kt + (c0 & 3) * 8, Bs + c0 * 8);
            gload_lds16(Bb + (size_t)(c1 >> 2) * K + kt + (c1 & 3) * 8, Bs + c1 * 8);
        }
        __syncthreads();
        s16x8 af[4], bfr[4];
        #pragma unroll
        for (int mi = 0; mi < 4; mi++)
            af[mi] = *(const s16x8*)(As + (wm * 64 + mi * 16 + lr) * 32 + lh * 8);
        #pragma unroll
        for (int ni = 0; ni < 4; ni++)
            bfr[ni] = *(const s16x8*)(Bs + (wn * 64 + ni * 16 + lr) * 32 + lh * 8);
        #pragma unroll
        for (int mi = 0; mi < 4; mi++)
            #pragma unroll
            for (int ni = 0; ni < 4; ni++)
                acc[mi][ni] = __builtin_amdgcn_mfma_f32_16x16x32_bf16(
                    af[mi], bfr[ni], acc[mi][ni], 0, 0, 0);
    }

    const int r0 = bm * 128 + wm * 64;
    const int c0 = bn * 128 + wn * 64;
    if constexpr (OBF16) {
        unsigned short* O = (unsigned short*)Cout;
        #pragma unroll
        for (int mi = 0; mi < 4; mi++)
            #pragma unroll
            for (int ni = 0; ni < 4; ni++)
                #pragma unroll
                for (int i = 0; i < 4; i++)
                    O[(size_t)(r0 + mi * 16 + lh * 4 + i) * Nn + c0 + ni * 16 + lr] =
                        f2bf(acc[mi][ni][i]);
    } else {
        float* O = (float*)Cout;
        #pragma unroll
        for (int mi = 0; mi < 4; mi++)
            #pragma unroll
            for (int ni = 0; ni < 4; ni++)
                #pragma unroll
                for (int i = 0; i < 4; i++) {
                    int cc = c0 + ni * 16 + lr;
                    float v = acc[mi][ni][i];
                    if constexpr (BIAS) v += bias[cc];
                    O[(size_t)(r0 + mi * 16 + lh * 4 + i) * Nn + cc] = v;
                }
    }
}

// ---------------- V transpose: vt[bh][d][k] = V[b,h,k,d] ---------------------
__global__ __launch_bounds__(256) void transpose_v(
    const unsigned short* __restrict__ qkv, unsigned short* __restrict__ vt)
{
    __shared__ unsigned short tile[64][72];   // +8 pad
    const int kt = blockIdx.x, bh = blockIdx.y;
    const int b = bh / TH, h = bh % TH;
    const int t = threadIdx.x;
    const unsigned short* src = qkv + (size_t)(b * TN + kt * 64) * TNQKV + 2 * TC + h * THD;
    #pragma unroll
    for (int c = t; c < 512; c += 256) {
        int k = c >> 3, d8 = c & 7;
        *(s16x8*)&tile[k][d8 * 8] = *(const s16x8*)(src + (size_t)k * TNQKV + d8 * 8);
    }
    __syncthreads();
    unsigned short* dst = vt + (size_t)bh * THD * TN + kt * 64;
    #pragma unroll
    for (int c = t; c < 512; c += 256) {
        int d = c >> 3, k8 = c & 7;
        s16x8 v;
        #pragma unroll
        for (int e = 0; e < 8; e++) v[e] = tile[k8 * 8 + e][d];
        *(s16x8*)(dst + (size_t)d * TN + k8 * 8) = v;
    }
}

// ---------------- Flash attention, swapped-QK^T (S^T = K·Q^T) ----------------
// 4 waves x 16 q-rows = 64-row Q tile; KVBLK=64; lane owns one q-row (q=lr).
// 1-D grid with XCD swizzle: each XCD owns 12 complete heads (L2-resident K/V).
__global__ __launch_bounds__(256) void attn_kernel(
    const unsigned short* __restrict__ qkv,
    const unsigned short* __restrict__ vt,
    unsigned short* __restrict__ out)     // [8192][768] bf16
{
    const int bid = blockIdx.x;           // 0..1535
    const int vid = (bid & 7) * 192 + (bid >> 3);
    const int bh = vid >> 4;              // 0..95
    const int qt = vid & 15;              // 0..15
    const int b = bh / TH, h = bh % TH;
    const int t = threadIdx.x, w = t >> 6, l = t & 63;
    const int lr = l & 15, lh = l >> 4;
    const int qbase = qt * 64 + w * 16;

    __shared__ unsigned short plds[4][16 * 72];  // per-wave P^ tile [q][k], stride 72

    // Q as B-operand fragments, pre-scaled by SCALE*log2e (so P = exp2(S'-m))
    const unsigned short* qptr = qkv + (size_t)(b * TN + qbase + lr) * TNQKV + h * THD;
    s16x8 bq[2];
    #pragma unroll
    for (int cj = 0; cj < 2; cj++) {
        s16x8 raw = *(const s16x8*)(qptr + cj * 32 + lh * 8);
        #pragma unroll
        for (int e = 0; e < 8; e++)
            bq[cj][e] = (short)f2bf(bf2f((unsigned short)raw[e]) * QSCALE_LOG2E);
    }

    f32x4 o[4] = {};          // O^T acc: q=lr, d = nd*16 + lh*4 + i
    float m2 = -1e30f, lsum = 0.f;

    const unsigned short* kbase = qkv + (size_t)(b * TN) * TNQKV + TC + h * THD;
    const unsigned short* vtb = vt + (size_t)bh * THD * TN;
    unsigned short* pw = plds[w];

    // ---- software pipeline: K tile for kt=0 preloaded ----
    s16x8 kc[4][2];
    #pragma unroll
    for (int kk = 0; kk < 4; kk++) {
        const unsigned short* kp = kbase + (size_t)(kk * 16 + lr) * TNQKV;
        kc[kk][0] = *(const s16x8*)(kp + lh * 8);
        kc[kk][1] = *(const s16x8*)(kp + 32 + lh * 8);
    }

    for (int kt = 0; kt < TN; kt += 64) {
        // --- issue V(t) loads early (independent of softmax) ---
        s16x8 vv[2][4];
        #pragma unroll
        for (int ktile = 0; ktile < 2; ktile++)
            #pragma unroll
            for (int nd = 0; nd < 4; nd++)
                vv[ktile][nd] = *(const s16x8*)(
                    vtb + (size_t)(nd * 16 + lr) * TN + kt + ktile * 32 + lh * 8);
        // --- issue K(t+1) prefetch (address clamped; last iter re-reads tile 0) ---
        const int ktn = (kt + 64) & (TN - 1);
        s16x8 kn[4][2];
        #pragma unroll
        for (int kk = 0; kk < 4; kk++) {
            const unsigned short* kp = kbase + (size_t)(ktn + kk * 16 + lr) * TNQKV;
            kn[kk][0] = *(const s16x8*)(kp + lh * 8);
            kn[kk][1] = *(const s16x8*)(kp + 32 + lh * 8);
        }

        // --- S^T = K Q^T for 64k x 16q: lane gets S'[q=lr][k=kk*16+lh*4+i] ---
        f32x4 s[4];
        #pragma unroll
        for (int kk = 0; kk < 4; kk++) {
            f32x4 z = {0.f, 0.f, 0.f, 0.f};
            z = __builtin_amdgcn_mfma_f32_16x16x32_bf16(kc[kk][0], bq[0], z, 0, 0, 0);
            z = __builtin_amdgcn_mfma_f32_16x16x32_bf16(kc[kk][1], bq[1], z, 0, 0, 0);
            s[kk] = z;
        }
        #pragma unroll
        for (int kk = 0; kk < 4; kk++) {
            kc[kk][0] = kn[kk][0];
            kc[kk][1] = kn[kk][1];
        }

        // --- online softmax (log2 domain), in-lane tree + 2 shuffles ---
        float v[16];
        #pragma unroll
        for (int kk = 0; kk < 4; kk++)
            #pragma unroll
            for (int i = 0; i < 4; i++) v[kk * 4 + i] = s[kk][i];
        #pragma unroll
        for (int st = 8; st >= 1; st >>= 1)
            #pragma unroll
            for (int j = 0; j < st; j++) v[j] = fmaxf(v[j], v[j + st]);
        float mx = v[0];
        mx = fmaxf(mx, __shfl_xor(mx, 16, 64));
        mx = fmaxf(mx, __shfl_xor(mx, 32, 64));
        // defer-max: skip rescale while tile max stays within THR of running max
        if (!__all(mx <= m2 + THR_BITS)) {
            float newm = fmaxf(m2, mx);
            float corr = __builtin_amdgcn_exp2f(m2 - newm);
            m2 = newm;
            lsum *= corr;
            #pragma unroll
            for (int nd = 0; nd < 4; nd++)
                #pragma unroll
                for (int i = 0; i < 4; i++) o[nd][i] *= corr;
        }
        float a[16];
        #pragma unroll
        for (int kk = 0; kk < 4; kk++)
            #pragma unroll
            for (int i = 0; i < 4; i++) {
                float p = __builtin_amdgcn_exp2f(s[kk][i] - m2);
                s[kk][i] = p;
                a[kk * 4 + i] = p;
            }
        #pragma unroll
        for (int st = 8; st >= 1; st >>= 1)
            #pragma unroll
            for (int j = 0; j < st; j++) a[j] += a[j + st];
        float ps = a[0];
        ps += __shfl_xor(ps, 16, 64);
        ps += __shfl_xor(ps, 32, 64);
        lsum += ps;

        // --- P^T -> LDS tile [q=lr][k], 8B packed writes ---
        #pragma unroll
        for (int kk = 0; kk < 4; kk++) {
            s16x4 pk;
            #pragma unroll
            for (int i = 0; i < 4; i++) pk[i] = (short)f2bf(s[kk][i]);
            *(s16x4*)(pw + lr * 72 + kk * 16 + lh * 4) = pk;
        }
        // --- O^T += Vt P^T (A = Vt rows d from prefetched regs, B = P rows q) ---
        #pragma unroll
        for (int ktile = 0; ktile < 2; ktile++) {
            s16x8 bp = *(const s16x8*)(pw + lr * 72 + ktile * 32 + lh * 8);
            #pragma unroll
            for (int nd = 0; nd < 4; nd++)
                o[nd] = __builtin_amdgcn_mfma_f32_16x16x32_bf16(
                    vv[ktile][nd], bp, o[nd], 0, 0, 0);
        }
    }

    // epilogue: lane owns q=lr; d = nd*16 + lh*4 + i -> 8B packed stores
    float inv = 1.f / lsum;
    unsigned short* op = out + (size_t)(b * TN + qbase + lr) * TC + h * THD;
    #pragma unroll
    for (int nd = 0; nd < 4; nd++) {
        s16x4 r;
        #pragma unroll
        for (int i = 0; i < 4; i++) r[i] = (short)f2bf(o[nd][i] * inv);
        *(s16x4*)(op + nd * 16 + lh * 4) = r;
    }
}

extern "C" void kernel_launch(void* const* d_in, const int* in_sizes, int n_in,
                              void* d_out, int out_size, void* d_ws, size_t ws_size,
                              hipStream_t stream) {
    const float* x      = (const float*)d_in[0];
    const float* w_qkv  = (const float*)d_in[1];
    const float* w_proj = (const float*)d_in[2];
    const float* b_proj = (const float*)d_in[3];
    float* out = (float*)d_out;

    unsigned short* xb   = (unsigned short*)d_ws;
    unsigned short* wqb  = xb   + (size_t)TM * TC;
    unsigned short* wpb  = wqb  + (size_t)TNQKV * TC;
    unsigned short* qkvb = wpb  + (size_t)TC * TC;
    unsigned short* vtb  = qkvb + (size_t)TM * TNQKV;
    unsigned short* aob  = vtb  + (size_t)TB * TH * THD * TN;

    int n8;
    n8 = TM * TC / 8;
    cvt_kernel<<<(n8 + 255) / 256, 256, 0, stream>>>(x, xb, n8);
    n8 = TNQKV * TC / 8;
    cvt_kernel<<<(n8 + 255) / 256, 256, 0, stream>>>(w_qkv, wqb, n8);
    n8 = TC * TC / 8;
    cvt_kernel<<<(n8 + 255) / 256, 256, 0, stream>>>(w_proj, wpb, n8);

    gemm_bt<false, true><<<dim3(TM / 128, TNQKV / 128), 256, 0, stream>>>(
        xb, wqb, (void*)qkvb, nullptr, TM, TNQKV, TC);

    transpose_v<<<dim3(TN / 64, TB * TH), 256, 0, stream>>>(qkvb, vtb);

    attn_kernel<<<1536, 256, 0, stream>>>(qkvb, vtb, aob);

    gemm_bt<true, false><<<dim3(TM / 128, TC / 128), 256, 0, stream>>>(
        aob, wpb, (void*)out, b_proj, TM, TC, TC);
}

// Round 7
// 150.074 us; speedup vs baseline: 1.7767x; 1.7767x over previous
//
#include <hip/hip_runtime.h>
#include <hip/hip_bf16.h>
#include <cstdint>

#define TB 8
#define TN 1024
#define TC 768
#define TH 12
#define THD 64
#define TM (TB*TN)          // 8192 rows
#define TNQKV (3*TC)        // 2304
// SCALE * log2(e) = 0.125 * 1.4426950408889634
#define QSCALE_LOG2E 0.18033688011112042f
// defer-max threshold: 8 nats in log2 units
#define THR_BITS 11.541560327111708f

typedef __attribute__((ext_vector_type(8))) short s16x8;
typedef __attribute__((ext_vector_type(4))) short s16x4;
typedef __attribute__((ext_vector_type(4))) float f32x4;

__device__ __forceinline__ unsigned short f2bf(float f) {
    union { float f; unsigned int u; } v; v.f = f;
    unsigned int u = v.u;
    return (unsigned short)((u + 0x7FFFu + ((u >> 16) & 1u)) >> 16);
}

__device__ __forceinline__ float bf2f(unsigned short h) {
    union { float f; unsigned int u; } v; v.u = ((unsigned int)h) << 16;
    return v.f;
}

__device__ __forceinline__ void gload_lds16(const unsigned short* g, unsigned short* l) {
    __builtin_amdgcn_global_load_lds(
        (const __attribute__((address_space(1))) unsigned int*)g,
        (__attribute__((address_space(3))) unsigned int*)l,
        16, 0, 0);
}

// ---------------- f32 -> bf16 conversion (vectorized, memory-bound) ----------
__global__ __launch_bounds__(256) void cvt_kernel(const float* __restrict__ in,
                                                  unsigned short* __restrict__ out,
                                                  int n8) {
    int i = blockIdx.x * blockDim.x + threadIdx.x;
    if (i >= n8) return;
    f32x4 a = *(const f32x4*)(in + (size_t)i * 8);
    f32x4 b = *(const f32x4*)(in + (size_t)i * 8 + 4);
    s16x8 r;
    #pragma unroll
    for (int e = 0; e < 4; e++) r[e] = (short)f2bf(a[e]);
    #pragma unroll
    for (int e = 0; e < 4; e++) r[4 + e] = (short)f2bf(b[e]);
    *(s16x8*)(out + (size_t)i * 8) = r;
}

// ---------------- bf16 GEMM, C = A * B^T (+bias). m97-style 128x128 tile -----
template<bool BIAS, bool OBF16>
__global__ __launch_bounds__(256) void gemm_bt(
    const unsigned short* __restrict__ A,
    const unsigned short* __restrict__ Bm,
    void* __restrict__ Cout,
    const float* __restrict__ bias,
    int M, int Nn, int K)
{
    __shared__ unsigned short As[128 * 32];
    __shared__ unsigned short Bs[128 * 32];
    const int t = threadIdx.x;
    const int w = t >> 6, l = t & 63;
    const int lr = l & 15, lh = l >> 4;
    const int wm = w >> 1, wn = w & 1;     // 2x2 wave grid, 64x64 out per wave
    const int bm = blockIdx.x, bn = blockIdx.y;

    f32x4 acc[4][4] = {};

    const unsigned short* Ab = A + (size_t)bm * 128 * K;
    const unsigned short* Bb = Bm + (size_t)bn * 128 * K;

    for (int kt = 0; kt < K; kt += 32) {
        __syncthreads();
        {
            const int c0 = t, c1 = t + 256;
            gload_lds16(Ab + (size_t)(c0 >> 2) * K + kt + (c0 & 3) * 8, As + c0 * 8);
            gload_lds16(Ab + (size_t)(c1 >> 2) * K + kt + (c1 & 3) * 8, As + c1 * 8);
            gload_lds16(Bb + (size_t)(c0 >> 2) * K + kt + (c0 & 3) * 8, Bs + c0 * 8);
            gload_lds16(Bb + (size_t)(c1 >> 2) * K + kt + (c1 & 3) * 8, Bs + c1 * 8);
        }
        __syncthreads();
        s16x8 af[4], bfr[4];
        #pragma unroll
        for (int mi = 0; mi < 4; mi++)
            af[mi] = *(const s16x8*)(As + (wm * 64 + mi * 16 + lr) * 32 + lh * 8);
        #pragma unroll
        for (int ni = 0; ni < 4; ni++)
            bfr[ni] = *(const s16x8*)(Bs + (wn * 64 + ni * 16 + lr) * 32 + lh * 8);
        #pragma unroll
        for (int mi = 0; mi < 4; mi++)
            #pragma unroll
            for (int ni = 0; ni < 4; ni++)
                acc[mi][ni] = __builtin_amdgcn_mfma_f32_16x16x32_bf16(
                    af[mi], bfr[ni], acc[mi][ni], 0, 0, 0);
    }

    const int r0 = bm * 128 + wm * 64;
    const int c0 = bn * 128 + wn * 64;
    if constexpr (OBF16) {
        unsigned short* O = (unsigned short*)Cout;
        #pragma unroll
        for (int mi = 0; mi < 4; mi++)
            #pragma unroll
            for (int ni = 0; ni < 4; ni++)
                #pragma unroll
                for (int i = 0; i < 4; i++)
                    O[(size_t)(r0 + mi * 16 + lh * 4 + i) * Nn + c0 + ni * 16 + lr] =
                        f2bf(acc[mi][ni][i]);
    } else {
        float* O = (float*)Cout;
        #pragma unroll
        for (int mi = 0; mi < 4; mi++)
            #pragma unroll
            for (int ni = 0; ni < 4; ni++)
                #pragma unroll
                for (int i = 0; i < 4; i++) {
                    int cc = c0 + ni * 16 + lr;
                    float v = acc[mi][ni][i];
                    if constexpr (BIAS) v += bias[cc];
                    O[(size_t)(r0 + mi * 16 + lh * 4 + i) * Nn + cc] = v;
                }
    }
}

// ---------------- V transpose: vt[bh][d][k] = V[b,h,k,d] ---------------------
__global__ __launch_bounds__(256) void transpose_v(
    const unsigned short* __restrict__ qkv, unsigned short* __restrict__ vt)
{
    __shared__ unsigned short tile[64][72];   // +8 pad
    const int kt = blockIdx.x, bh = blockIdx.y;
    const int b = bh / TH, h = bh % TH;
    const int t = threadIdx.x;
    const unsigned short* src = qkv + (size_t)(b * TN + kt * 64) * TNQKV + 2 * TC + h * THD;
    #pragma unroll
    for (int c = t; c < 512; c += 256) {
        int k = c >> 3, d8 = c & 7;
        *(s16x8*)&tile[k][d8 * 8] = *(const s16x8*)(src + (size_t)k * TNQKV + d8 * 8);
    }
    __syncthreads();
    unsigned short* dst = vt + (size_t)bh * THD * TN + kt * 64;
    #pragma unroll
    for (int c = t; c < 512; c += 256) {
        int d = c >> 3, k8 = c & 7;
        s16x8 v;
        #pragma unroll
        for (int e = 0; e < 8; e++) v[e] = tile[k8 * 8 + e][d];
        *(s16x8*)(dst + (size_t)d * TN + k8 * 8) = v;
    }
}

// ---------------- Flash attention, swapped-QK^T, LDS-staged K/V --------------
// 4 waves x 16 q-rows; KVBLK=64; K/V tiles double-buffered in LDS, staged with
// coalesced global_load_lds (pre-swizzled source, XOR-swizzled ds_read).
__global__ __launch_bounds__(256) void attn_kernel(
    const unsigned short* __restrict__ qkv,
    const unsigned short* __restrict__ vt,
    unsigned short* __restrict__ out)     // [8192][768] bf16
{
    const int bid = blockIdx.x;           // 0..1535
    const int vid = (bid & 7) * 192 + (bid >> 3);
    const int bh = vid >> 4;              // 0..95
    const int qt = vid & 15;              // 0..15
    const int b = bh / TH, h = bh % TH;
    const int t = threadIdx.x, w = t >> 6, l = t & 63;
    const int lr = l & 15, lh = l >> 4;
    const int qbase = qt * 64 + w * 16;

    // K tile: [key 0..63][d 0..63], V tile: [d 0..63][k 0..63]; 16B-chunk XOR swizzle
    __shared__ unsigned short Kbuf[2][64 * 64];
    __shared__ unsigned short Vbuf[2][64 * 64];
    __shared__ unsigned short plds[4][16 * 72];  // P^T row = 64 halfs + 8 pad

    const unsigned short* kbase = qkv + (size_t)(b * TN) * TNQKV + TC + h * THD;
    const unsigned short* vtb = vt + (size_t)bh * THD * TN;

    // staging geometry: wave w covers rows 16w..16w+15 of both tiles (2 instrs each)
    const int srow_lo = (l >> 3);              // 0..7 within 8-row group
    const int schunk = (l & 7) ^ srow_lo;      // pre-swizzled 16B-chunk (involution)
    const int j0 = 2 * w;

    // Q as B-operand fragments, pre-scaled by SCALE*log2e (so P = exp2(S'-m))
    const unsigned short* qptr = qkv + (size_t)(b * TN + qbase + lr) * TNQKV + h * THD;
    s16x8 bq[2];
    #pragma unroll
    for (int cj = 0; cj < 2; cj++) {
        s16x8 raw = *(const s16x8*)(qptr + cj * 32 + lh * 8);
        #pragma unroll
        for (int e = 0; e < 8; e++)
            bq[cj][e] = (short)f2bf(bf2f((unsigned short)raw[e]) * QSCALE_LOG2E);
    }

    f32x4 o[4] = {};          // O^T acc: q=lr, d = nd*16 + lh*4 + i
    float m2 = -1e30f, lsum = 0.f;
    unsigned short* pw = plds[w];

    // prologue: stage tile 0 into buf 0
    #pragma unroll
    for (int jj = 0; jj < 2; jj++) {
        const int j = j0 + jj, row = j * 8 + srow_lo;
        gload_lds16(kbase + (size_t)row * TNQKV + schunk * 8, &Kbuf[0][j * 512 + l * 8]);
        gload_lds16(vtb + (size_t)row * TN + schunk * 8, &Vbuf[0][j * 512 + l * 8]);
    }
    __syncthreads();

    for (int it = 0; it < 16; it++) {
        const int kt = it * 64;
        const int cur = it & 1, nxt = cur ^ 1;
        // --- issue next tile's staging (clamped; last iter restages tile 0) ---
        {
            const int ktn = (kt + 64) & (TN - 1);
            #pragma unroll
            for (int jj = 0; jj < 2; jj++) {
                const int j = j0 + jj, row = j * 8 + srow_lo;
                gload_lds16(kbase + (size_t)(ktn + row) * TNQKV + schunk * 8,
                            &Kbuf[nxt][j * 512 + l * 8]);
                gload_lds16(vtb + (size_t)row * TN + ktn + schunk * 8,
                            &Vbuf[nxt][j * 512 + l * 8]);
            }
        }
        const unsigned short* Kc = Kbuf[cur];
        const unsigned short* Vc = Vbuf[cur];

        // --- S^T = K Q^T for 64k x 16q: lane gets S'[q=lr][k=kk*16+lh*4+i] ---
        f32x4 s[4];
        #pragma unroll
        for (int kk = 0; kk < 4; kk++) {
            const int r = kk * 16 + lr;
            s16x8 ak0 = *(const s16x8*)(Kc + r * 64 + ((lh ^ (lr & 7)) * 8));
            s16x8 ak1 = *(const s16x8*)(Kc + r * 64 + (((4 + lh) ^ (lr & 7)) * 8));
            f32x4 z = {0.f, 0.f, 0.f, 0.f};
            z = __builtin_amdgcn_mfma_f32_16x16x32_bf16(ak0, bq[0], z, 0, 0, 0);
            z = __builtin_amdgcn_mfma_f32_16x16x32_bf16(ak1, bq[1], z, 0, 0, 0);
            s[kk] = z;
        }

        // --- online softmax (log2 domain), in-lane tree + 2 shuffles ---
        float v[16];
        #pragma unroll
        for (int kk = 0; kk < 4; kk++)
            #pragma unroll
            for (int i = 0; i < 4; i++) v[kk * 4 + i] = s[kk][i];
        #pragma unroll
        for (int st = 8; st >= 1; st >>= 1)
            #pragma unroll
            for (int j = 0; j < st; j++) v[j] = fmaxf(v[j], v[j + st]);
        float mx = v[0];
        mx = fmaxf(mx, __shfl_xor(mx, 16, 64));
        mx = fmaxf(mx, __shfl_xor(mx, 32, 64));
        if (!__all(mx <= m2 + THR_BITS)) {
            float newm = fmaxf(m2, mx);
            float corr = __builtin_amdgcn_exp2f(m2 - newm);
            m2 = newm;
            lsum *= corr;
            #pragma unroll
            for (int nd = 0; nd < 4; nd++)
                #pragma unroll
                for (int i = 0; i < 4; i++) o[nd][i] *= corr;
        }
        float a[16];
        #pragma unroll
        for (int kk = 0; kk < 4; kk++)
            #pragma unroll
            for (int i = 0; i < 4; i++) {
                float p = __builtin_amdgcn_exp2f(s[kk][i] - m2);
                s[kk][i] = p;
                a[kk * 4 + i] = p;
            }
        #pragma unroll
        for (int st = 8; st >= 1; st >>= 1)
            #pragma unroll
            for (int j = 0; j < st; j++) a[j] += a[j + st];
        float ps = a[0];
        ps += __shfl_xor(ps, 16, 64);
        ps += __shfl_xor(ps, 32, 64);
        lsum += ps;

        // --- P^T -> LDS tile [q=lr][k], 8B packed writes (stride 72) ---
        #pragma unroll
        for (int kk = 0; kk < 4; kk++) {
            s16x4 pk;
            #pragma unroll
            for (int i = 0; i < 4; i++) pk[i] = (short)f2bf(s[kk][i]);
            *(s16x4*)(pw + lr * 72 + kk * 16 + lh * 4) = pk;
        }
        // --- O^T += Vt P^T (A = Vt rows d from LDS, B = P rows q) ---
        #pragma unroll
        for (int ktile = 0; ktile < 2; ktile++) {
            s16x8 bp = *(const s16x8*)(pw + lr * 72 + ktile * 32 + lh * 8);
            #pragma unroll
            for (int nd = 0; nd < 4; nd++) {
                const int d = nd * 16 + lr;
                s16x8 av = *(const s16x8*)(
                    Vc + d * 64 + ((((ktile << 2) + lh) ^ (lr & 7)) * 8));
                o[nd] = __builtin_amdgcn_mfma_f32_16x16x32_bf16(av, bp, o[nd], 0, 0, 0);
            }
        }
        __syncthreads();   // drains staging vmcnt + protects buffer swap
    }

    // epilogue: lane owns q=lr; d = nd*16 + lh*4 + i -> 8B packed stores
    float inv = 1.f / lsum;
    unsigned short* op = out + (size_t)(b * TN + qbase + lr) * TC + h * THD;
    #pragma unroll
    for (int nd = 0; nd < 4; nd++) {
        s16x4 r;
        #pragma unroll
        for (int i = 0; i < 4; i++) r[i] = (short)f2bf(o[nd][i] * inv);
        *(s16x4*)(op + nd * 16 + lh * 4) = r;
    }
}

extern "C" void kernel_launch(void* const* d_in, const int* in_sizes, int n_in,
                              void* d_out, int out_size, void* d_ws, size_t ws_size,
                              hipStream_t stream) {
    const float* x      = (const float*)d_in[0];
    const float* w_qkv  = (const float*)d_in[1];
    const float* w_proj = (const float*)d_in[2];
    const float* b_proj = (const float*)d_in[3];
    float* out = (float*)d_out;

    unsigned short* xb   = (unsigned short*)d_ws;
    unsigned short* wqb  = xb   + (size_t)TM * TC;
    unsigned short* wpb  = wqb  + (size_t)TNQKV * TC;
    unsigned short* qkvb = wpb  + (size_t)TC * TC;
    unsigned short* vtb  = qkvb + (size_t)TM * TNQKV;
    unsigned short* aob  = vtb  + (size_t)TB * TH * THD * TN;

    int n8;
    n8 = TM * TC / 8;
    cvt_kernel<<<(n8 + 255) / 256, 256, 0, stream>>>(x, xb, n8);
    n8 = TNQKV * TC / 8;
    cvt_kernel<<<(n8 + 255) / 256, 256, 0, stream>>>(w_qkv, wqb, n8);
    n8 = TC * TC / 8;
    cvt_kernel<<<(n8 + 255) / 256, 256, 0, stream>>>(w_proj, wpb, n8);

    gemm_bt<false, true><<<dim3(TM / 128, TNQKV / 128), 256, 0, stream>>>(
        xb, wqb, (void*)qkvb, nullptr, TM, TNQKV, TC);

    transpose_v<<<dim3(TN / 64, TB * TH), 256, 0, stream>>>(qkvb, vtb);

    attn_kernel<<<1536, 256, 0, stream>>>(qkvb, vtb, aob);

    gemm_bt<true, false><<<dim3(TM / 128, TC / 128), 256, 0, stream>>>(
        aob, wpb, (void*)out, b_proj, TM, TC, TC);
}

// Round 8
// 141.490 us; speedup vs baseline: 1.8845x; 1.0607x over previous
//
#include <hip/hip_runtime.h>
#include <hip/hip_bf16.h>
#include <cstdint>

#define TB 8
#define TN 1024
#define TC 768
#define TH 12
#define THD 64
#define TM (TB*TN)          // 8192 rows
#define TNQKV (3*TC)        // 2304
// SCALE * log2(e) = 0.125 * 1.4426950408889634
#define QSCALE_LOG2E 0.18033688011112042f
// defer-max threshold: 8 nats in log2 units
#define THR_BITS 11.541560327111708f

typedef __attribute__((ext_vector_type(8))) short s16x8;
typedef __attribute__((ext_vector_type(4))) short s16x4;
typedef __attribute__((ext_vector_type(4))) float f32x4;
typedef __attribute__((ext_vector_type(2))) unsigned int u32x2;

__device__ __forceinline__ unsigned short f2bf(float f) {
    union { float f; unsigned int u; } v; v.f = f;
    unsigned int u = v.u;
    return (unsigned short)((u + 0x7FFFu + ((u >> 16) & 1u)) >> 16);
}

__device__ __forceinline__ float bf2f(unsigned short h) {
    union { float f; unsigned int u; } v; v.u = ((unsigned int)h) << 16;
    return v.f;
}

// packed f32x2 -> bf16x2 (RNE), single instruction on gfx950
__device__ __forceinline__ unsigned int cvt_pk_bf16(float lo, float hi) {
    unsigned int r;
    asm("v_cvt_pk_bf16_f32 %0, %1, %2" : "=v"(r) : "v"(lo), "v"(hi));
    return r;
}

__device__ __forceinline__ void gload_lds16(const unsigned short* g, unsigned short* l) {
    __builtin_amdgcn_global_load_lds(
        (const __attribute__((address_space(1))) unsigned int*)g,
        (__attribute__((address_space(3))) unsigned int*)l,
        16, 0, 0);
}

// ---------------- f32 -> bf16 conversion (vectorized, memory-bound) ----------
__global__ __launch_bounds__(256) void cvt_kernel(const float* __restrict__ in,
                                                  unsigned short* __restrict__ out,
                                                  int n8) {
    int i = blockIdx.x * blockDim.x + threadIdx.x;
    if (i >= n8) return;
    f32x4 a = *(const f32x4*)(in + (size_t)i * 8);
    f32x4 b = *(const f32x4*)(in + (size_t)i * 8 + 4);
    s16x8 r;
    #pragma unroll
    for (int e = 0; e < 4; e++) r[e] = (short)f2bf(a[e]);
    #pragma unroll
    for (int e = 0; e < 4; e++) r[4 + e] = (short)f2bf(b[e]);
    *(s16x8*)(out + (size_t)i * 8) = r;
}

// ---------------- bf16 GEMM, C = A * B^T (+bias). m97-style 128x128 tile -----
template<bool BIAS, bool OBF16>
__global__ __launch_bounds__(256) void gemm_bt(
    const unsigned short* __restrict__ A,
    const unsigned short* __restrict__ Bm,
    void* __restrict__ Cout,
    const float* __restrict__ bias,
    int M, int Nn, int K)
{
    __shared__ unsigned short As[128 * 32];
    __shared__ unsigned short Bs[128 * 32];
    const int t = threadIdx.x;
    const int w = t >> 6, l = t & 63;
    const int lr = l & 15, lh = l >> 4;
    const int wm = w >> 1, wn = w & 1;     // 2x2 wave grid, 64x64 out per wave
    const int bm = blockIdx.x, bn = blockIdx.y;

    f32x4 acc[4][4] = {};

    const unsigned short* Ab = A + (size_t)bm * 128 * K;
    const unsigned short* Bb = Bm + (size_t)bn * 128 * K;

    for (int kt = 0; kt < K; kt += 32) {
        __syncthreads();
        {
            const int c0 = t, c1 = t + 256;
            gload_lds16(Ab + (size_t)(c0 >> 2) * K + kt + (c0 & 3) * 8, As + c0 * 8);
            gload_lds16(Ab + (size_t)(c1 >> 2) * K + kt + (c1 & 3) * 8, As + c1 * 8);
            gload_lds16(Bb + (size_t)(c0 >> 2) * K + kt + (c0 & 3) * 8, Bs + c0 * 8);
            gload_lds16(Bb + (size_t)(c1 >> 2) * K + kt + (c1 & 3) * 8, Bs + c1 * 8);
        }
        __syncthreads();
        s16x8 af[4], bfr[4];
        #pragma unroll
        for (int mi = 0; mi < 4; mi++)
            af[mi] = *(const s16x8*)(As + (wm * 64 + mi * 16 + lr) * 32 + lh * 8);
        #pragma unroll
        for (int ni = 0; ni < 4; ni++)
            bfr[ni] = *(const s16x8*)(Bs + (wn * 64 + ni * 16 + lr) * 32 + lh * 8);
        #pragma unroll
        for (int mi = 0; mi < 4; mi++)
            #pragma unroll
            for (int ni = 0; ni < 4; ni++)
                acc[mi][ni] = __builtin_amdgcn_mfma_f32_16x16x32_bf16(
                    af[mi], bfr[ni], acc[mi][ni], 0, 0, 0);
    }

    const int r0 = bm * 128 + wm * 64;
    const int c0 = bn * 128 + wn * 64;
    if constexpr (OBF16) {
        unsigned short* O = (unsigned short*)Cout;
        #pragma unroll
        for (int mi = 0; mi < 4; mi++)
            #pragma unroll
            for (int ni = 0; ni < 4; ni++)
                #pragma unroll
                for (int i = 0; i < 4; i++)
                    O[(size_t)(r0 + mi * 16 + lh * 4 + i) * Nn + c0 + ni * 16 + lr] =
                        f2bf(acc[mi][ni][i]);
    } else {
        float* O = (float*)Cout;
        #pragma unroll
        for (int mi = 0; mi < 4; mi++)
            #pragma unroll
            for (int ni = 0; ni < 4; ni++)
                #pragma unroll
                for (int i = 0; i < 4; i++) {
                    int cc = c0 + ni * 16 + lr;
                    float v = acc[mi][ni][i];
                    if constexpr (BIAS) v += bias[cc];
                    O[(size_t)(r0 + mi * 16 + lh * 4 + i) * Nn + cc] = v;
                }
    }
}

// ---------------- V transpose: vt[bh][d][k] = V[b,h,k,d] ---------------------
__global__ __launch_bounds__(256) void transpose_v(
    const unsigned short* __restrict__ qkv, unsigned short* __restrict__ vt)
{
    __shared__ unsigned short tile[64][72];   // +8 pad
    const int kt = blockIdx.x, bh = blockIdx.y;
    const int b = bh / TH, h = bh % TH;
    const int t = threadIdx.x;
    const unsigned short* src = qkv + (size_t)(b * TN + kt * 64) * TNQKV + 2 * TC + h * THD;
    #pragma unroll
    for (int c = t; c < 512; c += 256) {
        int k = c >> 3, d8 = c & 7;
        *(s16x8*)&tile[k][d8 * 8] = *(const s16x8*)(src + (size_t)k * TNQKV + d8 * 8);
    }
    __syncthreads();
    unsigned short* dst = vt + (size_t)bh * THD * TN + kt * 64;
    #pragma unroll
    for (int c = t; c < 512; c += 256) {
        int d = c >> 3, k8 = c & 7;
        s16x8 v;
        #pragma unroll
        for (int e = 0; e < 8; e++) v[e] = tile[k8 * 8 + e][d];
        *(s16x8*)(dst + (size_t)d * TN + k8 * 8) = v;
    }
}

// ---------------- Flash attention, swapped-QK^T, LDS-staged K/V --------------
// 4 waves x 16 q-rows; KVBLK=64; K/V double-buffered in LDS (coalesced
// global_load_lds, XOR-swizzled reads); P via swizzled LDS; cvt_pk packing;
// shuffle-free defer-max common path; deferred lsum reduce.
__global__ __launch_bounds__(256) void attn_kernel(
    const unsigned short* __restrict__ qkv,
    const unsigned short* __restrict__ vt,
    unsigned short* __restrict__ out)     // [8192][768] bf16
{
    const int bid = blockIdx.x;           // 0..1535
    const int vid = (bid & 7) * 192 + (bid >> 3);
    const int bh = vid >> 4;              // 0..95
    const int qt = vid & 15;              // 0..15
    const int b = bh / TH, h = bh % TH;
    const int t = threadIdx.x, w = t >> 6, l = t & 63;
    const int lr = l & 15, lh = l >> 4;
    const int qbase = qt * 64 + w * 16;

    __shared__ unsigned short Kbuf[2][64 * 64];
    __shared__ unsigned short Vbuf[2][64 * 64];
    __shared__ unsigned short plds[4][16 * 64];  // swizzled, no pad -> 40960 B total

    const unsigned short* kbase = qkv + (size_t)(b * TN) * TNQKV + TC + h * THD;
    const unsigned short* vtb = vt + (size_t)bh * THD * TN;

    // staging geometry: wave w covers rows 16w..16w+15 of both tiles
    const int srow_lo = (l >> 3);              // 0..7 within 8-row group
    const int schunk = (l & 7) ^ srow_lo;      // pre-swizzled 16B-chunk (involution)
    const int j0 = 2 * w;

    // Q as B-operand fragments, pre-scaled by SCALE*log2e (so P = exp2(S'-m))
    const unsigned short* qptr = qkv + (size_t)(b * TN + qbase + lr) * TNQKV + h * THD;
    s16x8 bq[2];
    #pragma unroll
    for (int cj = 0; cj < 2; cj++) {
        s16x8 raw = *(const s16x8*)(qptr + cj * 32 + lh * 8);
        #pragma unroll
        for (int e = 0; e < 8; e++)
            bq[cj][e] = (short)f2bf(bf2f((unsigned short)raw[e]) * QSCALE_LOG2E);
    }

    f32x4 o[4] = {};          // O^T acc: q=lr, d = nd*16 + lh*4 + i
    float m2 = -1e30f, lsum = 0.f;   // lsum = per-lane partial (reduced at end)
    unsigned short* pw = plds[w];
    const int lr7 = lr & 7;

    // prologue: stage tile 0 into buf 0
    #pragma unroll
    for (int jj = 0; jj < 2; jj++) {
        const int j = j0 + jj, row = j * 8 + srow_lo;
        gload_lds16(kbase + (size_t)row * TNQKV + schunk * 8, &Kbuf[0][j * 512 + l * 8]);
        gload_lds16(vtb + (size_t)row * TN + schunk * 8, &Vbuf[0][j * 512 + l * 8]);
    }
    __syncthreads();

    for (int it = 0; it < 16; it++) {
        const int kt = it * 64;
        const int cur = it & 1, nxt = cur ^ 1;
        // --- issue next tile's staging (last iter restages tile 0, harmless) ---
        {
            const int ktn = (kt + 64) & (TN - 1);
            #pragma unroll
            for (int jj = 0; jj < 2; jj++) {
                const int j = j0 + jj, row = j * 8 + srow_lo;
                gload_lds16(kbase + (size_t)(ktn + row) * TNQKV + schunk * 8,
                            &Kbuf[nxt][j * 512 + l * 8]);
                gload_lds16(vtb + (size_t)row * TN + ktn + schunk * 8,
                            &Vbuf[nxt][j * 512 + l * 8]);
            }
        }
        const unsigned short* Kc = Kbuf[cur];
        const unsigned short* Vc = Vbuf[cur];

        // --- S^T = K Q^T for 64k x 16q: lane gets S'[q=lr][k=kk*16+lh*4+i] ---
        f32x4 s[4];
        #pragma unroll
        for (int kk = 0; kk < 4; kk++) {
            const int r = kk * 16 + lr;
            s16x8 ak0 = *(const s16x8*)(Kc + r * 64 + ((lh ^ lr7) * 8));
            s16x8 ak1 = *(const s16x8*)(Kc + r * 64 + (((4 + lh) ^ lr7) * 8));
            f32x4 z = {0.f, 0.f, 0.f, 0.f};
            z = __builtin_amdgcn_mfma_f32_16x16x32_bf16(ak0, bq[0], z, 0, 0, 0);
            z = __builtin_amdgcn_mfma_f32_16x16x32_bf16(ak1, bq[1], z, 0, 0, 0);
            s[kk] = z;
        }

        // --- in-lane max (max3-friendly chain), shuffle-free defer-max test ---
        float v[16];
        #pragma unroll
        for (int kk = 0; kk < 4; kk++)
            #pragma unroll
            for (int i = 0; i < 4; i++) v[kk * 4 + i] = s[kk][i];
        float mx = fmaxf(fmaxf(v[0], v[1]), v[2]);
        #pragma unroll
        for (int j = 3; j + 1 < 16; j += 2) mx = fmaxf(fmaxf(mx, v[j]), v[j + 1]);
        mx = fmaxf(mx, v[15]);
        if (!__all(mx <= m2 + THR_BITS)) {
            float rmx = fmaxf(mx, __shfl_xor(mx, 16, 64));
            rmx = fmaxf(rmx, __shfl_xor(rmx, 32, 64));
            float newm = fmaxf(m2, rmx);
            float corr = __builtin_amdgcn_exp2f(m2 - newm);
            m2 = newm;
            lsum *= corr;
            #pragma unroll
            for (int nd = 0; nd < 4; nd++)
                #pragma unroll
                for (int i = 0; i < 4; i++) o[nd][i] *= corr;
        }
        float a[16];
        #pragma unroll
        for (int kk = 0; kk < 4; kk++)
            #pragma unroll
            for (int i = 0; i < 4; i++) {
                float p = __builtin_amdgcn_exp2f(s[kk][i] - m2);
                s[kk][i] = p;
                a[kk * 4 + i] = p;
            }
        #pragma unroll
        for (int st = 8; st >= 1; st >>= 1)
            #pragma unroll
            for (int j = 0; j < st; j++) a[j] += a[j + st];
        lsum += a[0];      // per-lane partial; cross-lane reduce deferred

        // --- P^T -> swizzled LDS [q=lr][k], cvt_pk 8B packed writes ---
        #pragma unroll
        for (int kk = 0; kk < 4; kk++) {
            u32x2 pk;
            pk[0] = cvt_pk_bf16(s[kk][0], s[kk][1]);
            pk[1] = cvt_pk_bf16(s[kk][2], s[kk][3]);
            const int wch = ((kk << 1) + (lh >> 1)) ^ lr7;
            *(u32x2*)(pw + lr * 64 + wch * 8 + (lh & 1) * 4) = pk;
        }
        // --- O^T += Vt P^T (A = Vt rows d from LDS, B = P rows q) ---
        #pragma unroll
        for (int ktile = 0; ktile < 2; ktile++) {
            const int rch = ((ktile << 2) + lh) ^ lr7;
            s16x8 bp = *(const s16x8*)(pw + lr * 64 + rch * 8);
            #pragma unroll
            for (int nd = 0; nd < 4; nd++) {
                const int d = nd * 16 + lr;
                s16x8 av = *(const s16x8*)(
                    Vc + d * 64 + ((((ktile << 2) + lh) ^ lr7) * 8));
                o[nd] = __builtin_amdgcn_mfma_f32_16x16x32_bf16(av, bp, o[nd], 0, 0, 0);
            }
        }
        __syncthreads();   // drains staging vmcnt + protects buffer swap
    }

    // epilogue: reduce lsum across lh groups, then packed stores
    lsum += __shfl_xor(lsum, 16, 64);
    lsum += __shfl_xor(lsum, 32, 64);
    float inv = 1.f / lsum;
    unsigned short* op = out + (size_t)(b * TN + qbase + lr) * TC + h * THD;
    #pragma unroll
    for (int nd = 0; nd < 4; nd++) {
        u32x2 r;
        r[0] = cvt_pk_bf16(o[nd][0] * inv, o[nd][1] * inv);
        r[1] = cvt_pk_bf16(o[nd][2] * inv, o[nd][3] * inv);
        *(u32x2*)(op + nd * 16 + lh * 4) = r;
    }
}

extern "C" void kernel_launch(void* const* d_in, const int* in_sizes, int n_in,
                              void* d_out, int out_size, void* d_ws, size_t ws_size,
                              hipStream_t stream) {
    const float* x      = (const float*)d_in[0];
    const float* w_qkv  = (const float*)d_in[1];
    const float* w_proj = (const float*)d_in[2];
    const float* b_proj = (const float*)d_in[3];
    float* out = (float*)d_out;

    unsigned short* xb   = (unsigned short*)d_ws;
    unsigned short* wqb  = xb   + (size_t)TM * TC;
    unsigned short* wpb  = wqb  + (size_t)TNQKV * TC;
    unsigned short* qkvb = wpb  + (size_t)TC * TC;
    unsigned short* vtb  = qkvb + (size_t)TM * TNQKV;
    unsigned short* aob  = vtb  + (size_t)TB * TH * THD * TN;

    int n8;
    n8 = TM * TC / 8;
    cvt_kernel<<<(n8 + 255) / 256, 256, 0, stream>>>(x, xb, n8);
    n8 = TNQKV * TC / 8;
    cvt_kernel<<<(n8 + 255) / 256, 256, 0, stream>>>(w_qkv, wqb, n8);
    n8 = TC * TC / 8;
    cvt_kernel<<<(n8 + 255) / 256, 256, 0, stream>>>(w_proj, wpb, n8);

    gemm_bt<false, true><<<dim3(TM / 128, TNQKV / 128), 256, 0, stream>>>(
        xb, wqb, (void*)qkvb, nullptr, TM, TNQKV, TC);

    transpose_v<<<dim3(TN / 64, TB * TH), 256, 0, stream>>>(qkvb, vtb);

    attn_kernel<<<1536, 256, 0, stream>>>(qkvb, vtb, aob);

    gemm_bt<true, false><<<dim3(TM / 128, TC / 128), 256, 0, stream>>>(
        aob, wpb, (void*)out, b_proj, TM, TC, TC);
}

// Round 9
// 133.398 us; speedup vs baseline: 1.9988x; 1.0607x over previous
//
#include <hip/hip_runtime.h>
#include <hip/hip_bf16.h>
#include <cstdint>

#define TB 8
#define TN 1024
#define TC 768
#define TH 12
#define THD 64
#define TM (TB*TN)          // 8192 rows
#define TNQKV (3*TC)        // 2304
// SCALE * log2(e) = 0.125 * 1.4426950408889634
#define QSCALE_LOG2E 0.18033688011112042f
// defer-max threshold: 8 nats in log2 units
#define THR_BITS 11.541560327111708f

typedef __attribute__((ext_vector_type(8))) short s16x8;
typedef __attribute__((ext_vector_type(4))) short s16x4;
typedef __attribute__((ext_vector_type(4))) float f32x4;
typedef __attribute__((ext_vector_type(2))) unsigned int u32x2;

__device__ __forceinline__ unsigned short f2bf(float f) {
    union { float f; unsigned int u; } v; v.f = f;
    unsigned int u = v.u;
    return (unsigned short)((u + 0x7FFFu + ((u >> 16) & 1u)) >> 16);
}

__device__ __forceinline__ float bf2f(unsigned short h) {
    union { float f; unsigned int u; } v; v.u = ((unsigned int)h) << 16;
    return v.f;
}

// packed f32x2 -> bf16x2 (RNE), single instruction on gfx950
__device__ __forceinline__ unsigned int cvt_pk_bf16(float lo, float hi) {
    unsigned int r;
    asm("v_cvt_pk_bf16_f32 %0, %1, %2" : "=v"(r) : "v"(lo), "v"(hi));
    return r;
}

__device__ __forceinline__ void gload_lds16(const unsigned short* g, unsigned short* l) {
    __builtin_amdgcn_global_load_lds(
        (const __attribute__((address_space(1))) unsigned int*)g,
        (__attribute__((address_space(3))) unsigned int*)l,
        16, 0, 0);
}

// ---------------- f32 -> bf16 conversion (vectorized, memory-bound) ----------
__global__ __launch_bounds__(256) void cvt_kernel(const float* __restrict__ in,
                                                  unsigned short* __restrict__ out,
                                                  int n8) {
    int i = blockIdx.x * blockDim.x + threadIdx.x;
    if (i >= n8) return;
    f32x4 a = *(const f32x4*)(in + (size_t)i * 8);
    f32x4 b = *(const f32x4*)(in + (size_t)i * 8 + 4);
    s16x8 r;
    #pragma unroll
    for (int e = 0; e < 4; e++) r[e] = (short)f2bf(a[e]);
    #pragma unroll
    for (int e = 0; e < 4; e++) r[4 + e] = (short)f2bf(b[e]);
    *(s16x8*)(out + (size_t)i * 8) = r;
}

// ---------------- bf16 GEMM, C = A * B^T (+bias). m97-style 128x128 tile -----
template<bool BIAS, bool OBF16>
__global__ __launch_bounds__(256) void gemm_bt(
    const unsigned short* __restrict__ A,
    const unsigned short* __restrict__ Bm,
    void* __restrict__ Cout,
    const float* __restrict__ bias,
    int M, int Nn, int K)
{
    __shared__ unsigned short As[128 * 32];
    __shared__ unsigned short Bs[128 * 32];
    const int t = threadIdx.x;
    const int w = t >> 6, l = t & 63;
    const int lr = l & 15, lh = l >> 4;
    const int wm = w >> 1, wn = w & 1;     // 2x2 wave grid, 64x64 out per wave
    const int bm = blockIdx.x, bn = blockIdx.y;

    f32x4 acc[4][4] = {};

    const unsigned short* Ab = A + (size_t)bm * 128 * K;
    const unsigned short* Bb = Bm + (size_t)bn * 128 * K;

    for (int kt = 0; kt < K; kt += 32) {
        __syncthreads();
        {
            const int c0 = t, c1 = t + 256;
            gload_lds16(Ab + (size_t)(c0 >> 2) * K + kt + (c0 & 3) * 8, As + c0 * 8);
            gload_lds16(Ab + (size_t)(c1 >> 2) * K + kt + (c1 & 3) * 8, As + c1 * 8);
            gload_lds16(Bb + (size_t)(c0 >> 2) * K + kt + (c0 & 3) * 8, Bs + c0 * 8);
            gload_lds16(Bb + (size_t)(c1 >> 2) * K + kt + (c1 & 3) * 8, Bs + c1 * 8);
        }
        __syncthreads();
        s16x8 af[4], bfr[4];
        #pragma unroll
        for (int mi = 0; mi < 4; mi++)
            af[mi] = *(const s16x8*)(As + (wm * 64 + mi * 16 + lr) * 32 + lh * 8);
        #pragma unroll
        for (int ni = 0; ni < 4; ni++)
            bfr[ni] = *(const s16x8*)(Bs + (wn * 64 + ni * 16 + lr) * 32 + lh * 8);
        #pragma unroll
        for (int mi = 0; mi < 4; mi++)
            #pragma unroll
            for (int ni = 0; ni < 4; ni++)
                acc[mi][ni] = __builtin_amdgcn_mfma_f32_16x16x32_bf16(
                    af[mi], bfr[ni], acc[mi][ni], 0, 0, 0);
    }

    const int r0 = bm * 128 + wm * 64;
    const int c0 = bn * 128 + wn * 64;
    if constexpr (OBF16) {
        unsigned short* O = (unsigned short*)Cout;
        #pragma unroll
        for (int mi = 0; mi < 4; mi++)
            #pragma unroll
            for (int ni = 0; ni < 4; ni++)
                #pragma unroll
                for (int i = 0; i < 4; i++)
                    O[(size_t)(r0 + mi * 16 + lh * 4 + i) * Nn + c0 + ni * 16 + lr] =
                        f2bf(acc[mi][ni][i]);
    } else {
        float* O = (float*)Cout;
        #pragma unroll
        for (int mi = 0; mi < 4; mi++)
            #pragma unroll
            for (int ni = 0; ni < 4; ni++)
                #pragma unroll
                for (int i = 0; i < 4; i++) {
                    int cc = c0 + ni * 16 + lr;
                    float v = acc[mi][ni][i];
                    if constexpr (BIAS) v += bias[cc];
                    O[(size_t)(r0 + mi * 16 + lh * 4 + i) * Nn + cc] = v;
                }
    }
}

// ---------------- V transpose: vt[bh][d][k] = V[b,h,k,d] ---------------------
__global__ __launch_bounds__(256) void transpose_v(
    const unsigned short* __restrict__ qkv, unsigned short* __restrict__ vt)
{
    __shared__ unsigned short tile[64][72];   // +8 pad
    const int kt = blockIdx.x, bh = blockIdx.y;
    const int b = bh / TH, h = bh % TH;
    const int t = threadIdx.x;
    const unsigned short* src = qkv + (size_t)(b * TN + kt * 64) * TNQKV + 2 * TC + h * THD;
    #pragma unroll
    for (int c = t; c < 512; c += 256) {
        int k = c >> 3, d8 = c & 7;
        *(s16x8*)&tile[k][d8 * 8] = *(const s16x8*)(src + (size_t)k * TNQKV + d8 * 8);
    }
    __syncthreads();
    unsigned short* dst = vt + (size_t)bh * THD * TN + kt * 64;
    #pragma unroll
    for (int c = t; c < 512; c += 256) {
        int d = c >> 3, k8 = c & 7;
        s16x8 v;
        #pragma unroll
        for (int e = 0; e < 8; e++) v[e] = tile[k8 * 8 + e][d];
        *(s16x8*)(dst + (size_t)d * TN + k8 * 8) = v;
    }
}

// ---------------- Flash attention, swapped-QK^T, LDS-staged K/V --------------
// 8 waves x 16 q-rows = 128-q tile; KVBLK=64; K/V double-buffered in LDS.
// grid = 768 = 3 blocks/CU exactly (all co-resident, zero tail).
__global__ __launch_bounds__(512) void attn_kernel(
    const unsigned short* __restrict__ qkv,
    const unsigned short* __restrict__ vt,
    unsigned short* __restrict__ out)     // [8192][768] bf16
{
    const int bid = blockIdx.x;           // 0..767
    const int vid = (bid & 7) * 96 + (bid >> 3);
    const int bh = vid >> 3;              // 0..95
    const int qt = vid & 7;               // 0..7
    const int b = bh / TH, h = bh % TH;
    const int t = threadIdx.x, w = t >> 6, l = t & 63;
    const int lr = l & 15, lh = l >> 4;
    const int qbase = qt * 128 + w * 16;

    __shared__ unsigned short Kbuf[2][64 * 64];
    __shared__ unsigned short Vbuf[2][64 * 64];
    __shared__ unsigned short plds[8][16 * 64];  // swizzled; total LDS = 48 KB

    const unsigned short* kbase = qkv + (size_t)(b * TN) * TNQKV + TC + h * THD;
    const unsigned short* vtb = vt + (size_t)bh * THD * TN;

    // staging geometry: wave w covers rows 8w..8w+7 of both tiles (1 instr each)
    const int srow_lo = (l >> 3);              // 0..7 within 8-row group
    const int schunk = (l & 7) ^ srow_lo;      // pre-swizzled 16B-chunk (involution)
    const int srow = w * 8 + srow_lo;
    const int sdst = w * 512 + l * 8;          // = srow*64 + (l&7)*8

    // Q as B-operand fragments, pre-scaled by SCALE*log2e (so P = exp2(S'-m))
    const unsigned short* qptr = qkv + (size_t)(b * TN + qbase + lr) * TNQKV + h * THD;
    s16x8 bq[2];
    #pragma unroll
    for (int cj = 0; cj < 2; cj++) {
        s16x8 raw = *(const s16x8*)(qptr + cj * 32 + lh * 8);
        #pragma unroll
        for (int e = 0; e < 8; e++)
            bq[cj][e] = (short)f2bf(bf2f((unsigned short)raw[e]) * QSCALE_LOG2E);
    }

    f32x4 o[4] = {};          // O^T acc: q=lr, d = nd*16 + lh*4 + i
    float m2 = -1e30f, lsum = 0.f;   // lsum = per-lane partial (reduced at end)
    unsigned short* pw = plds[w];
    const int lr7 = lr & 7;

    // prologue: stage tile 0 into buf 0
    gload_lds16(kbase + (size_t)srow * TNQKV + schunk * 8, &Kbuf[0][sdst]);
    gload_lds16(vtb + (size_t)srow * TN + schunk * 8, &Vbuf[0][sdst]);
    __syncthreads();

    for (int it = 0; it < 16; it++) {
        const int kt = it * 64;
        const int cur = it & 1, nxt = cur ^ 1;
        // --- issue next tile's staging (last iter restages tile 0, harmless) ---
        {
            const int ktn = (kt + 64) & (TN - 1);
            gload_lds16(kbase + (size_t)(ktn + srow) * TNQKV + schunk * 8, &Kbuf[nxt][sdst]);
            gload_lds16(vtb + (size_t)srow * TN + ktn + schunk * 8, &Vbuf[nxt][sdst]);
        }
        const unsigned short* Kc = Kbuf[cur];
        const unsigned short* Vc = Vbuf[cur];

        // --- S^T = K Q^T for 64k x 16q: lane gets S'[q=lr][k=kk*16+lh*4+i] ---
        f32x4 s[4];
        #pragma unroll
        for (int kk = 0; kk < 4; kk++) {
            const int r = kk * 16 + lr;
            s16x8 ak0 = *(const s16x8*)(Kc + r * 64 + ((lh ^ lr7) * 8));
            s16x8 ak1 = *(const s16x8*)(Kc + r * 64 + (((4 + lh) ^ lr7) * 8));
            f32x4 z = {0.f, 0.f, 0.f, 0.f};
            z = __builtin_amdgcn_mfma_f32_16x16x32_bf16(ak0, bq[0], z, 0, 0, 0);
            z = __builtin_amdgcn_mfma_f32_16x16x32_bf16(ak1, bq[1], z, 0, 0, 0);
            s[kk] = z;
        }

        // --- in-lane max (max3-friendly chain), shuffle-free defer-max test ---
        float v[16];
        #pragma unroll
        for (int kk = 0; kk < 4; kk++)
            #pragma unroll
            for (int i = 0; i < 4; i++) v[kk * 4 + i] = s[kk][i];
        float mx = fmaxf(fmaxf(v[0], v[1]), v[2]);
        #pragma unroll
        for (int j = 3; j + 1 < 16; j += 2) mx = fmaxf(fmaxf(mx, v[j]), v[j + 1]);
        mx = fmaxf(mx, v[15]);
        if (!__all(mx <= m2 + THR_BITS)) {
            float rmx = fmaxf(mx, __shfl_xor(mx, 16, 64));
            rmx = fmaxf(rmx, __shfl_xor(rmx, 32, 64));
            float newm = fmaxf(m2, rmx);
            float corr = __builtin_amdgcn_exp2f(m2 - newm);
            m2 = newm;
            lsum *= corr;
            #pragma unroll
            for (int nd = 0; nd < 4; nd++)
                #pragma unroll
                for (int i = 0; i < 4; i++) o[nd][i] *= corr;
        }
        float a[16];
        #pragma unroll
        for (int kk = 0; kk < 4; kk++)
            #pragma unroll
            for (int i = 0; i < 4; i++) {
                float p = __builtin_amdgcn_exp2f(s[kk][i] - m2);
                s[kk][i] = p;
                a[kk * 4 + i] = p;
            }
        #pragma unroll
        for (int st = 8; st >= 1; st >>= 1)
            #pragma unroll
            for (int j = 0; j < st; j++) a[j] += a[j + st];
        lsum += a[0];      // per-lane partial; cross-lane reduce deferred

        // --- P^T -> swizzled LDS [q=lr][k], cvt_pk 8B packed writes ---
        #pragma unroll
        for (int kk = 0; kk < 4; kk++) {
            u32x2 pk;
            pk[0] = cvt_pk_bf16(s[kk][0], s[kk][1]);
            pk[1] = cvt_pk_bf16(s[kk][2], s[kk][3]);
            const int wch = ((kk << 1) + (lh >> 1)) ^ lr7;
            *(u32x2*)(pw + lr * 64 + wch * 8 + (lh & 1) * 4) = pk;
        }
        // --- O^T += Vt P^T (A = Vt rows d from LDS, B = P rows q) ---
        #pragma unroll
        for (int ktile = 0; ktile < 2; ktile++) {
            const int rch = ((ktile << 2) + lh) ^ lr7;
            s16x8 bp = *(const s16x8*)(pw + lr * 64 + rch * 8);
            #pragma unroll
            for (int nd = 0; nd < 4; nd++) {
                const int d = nd * 16 + lr;
                s16x8 av = *(const s16x8*)(
                    Vc + d * 64 + ((((ktile << 2) + lh) ^ lr7) * 8));
                o[nd] = __builtin_amdgcn_mfma_f32_16x16x32_bf16(av, bp, o[nd], 0, 0, 0);
            }
        }
        __syncthreads();   // drains staging vmcnt + protects buffer swap
    }

    // epilogue: reduce lsum across lh groups, then packed stores
    lsum += __shfl_xor(lsum, 16, 64);
    lsum += __shfl_xor(lsum, 32, 64);
    float inv = 1.f / lsum;
    unsigned short* op = out + (size_t)(b * TN + qbase + lr) * TC + h * THD;
    #pragma unroll
    for (int nd = 0; nd < 4; nd++) {
        u32x2 r;
        r[0] = cvt_pk_bf16(o[nd][0] * inv, o[nd][1] * inv);
        r[1] = cvt_pk_bf16(o[nd][2] * inv, o[nd][3] * inv);
        *(u32x2*)(op + nd * 16 + lh * 4) = r;
    }
}

extern "C" void kernel_launch(void* const* d_in, const int* in_sizes, int n_in,
                              void* d_out, int out_size, void* d_ws, size_t ws_size,
                              hipStream_t stream) {
    const float* x      = (const float*)d_in[0];
    const float* w_qkv  = (const float*)d_in[1];
    const float* w_proj = (const float*)d_in[2];
    const float* b_proj = (const float*)d_in[3];
    float* out = (float*)d_out;

    unsigned short* xb   = (unsigned short*)d_ws;
    unsigned short* wqb  = xb   + (size_t)TM * TC;
    unsigned short* wpb  = wqb  + (size_t)TNQKV * TC;
    unsigned short* qkvb = wpb  + (size_t)TC * TC;
    unsigned short* vtb  = qkvb + (size_t)TM * TNQKV;
    unsigned short* aob  = vtb  + (size_t)TB * TH * THD * TN;

    int n8;
    n8 = TM * TC / 8;
    cvt_kernel<<<(n8 + 255) / 256, 256, 0, stream>>>(x, xb, n8);
    n8 = TNQKV * TC / 8;
    cvt_kernel<<<(n8 + 255) / 256, 256, 0, stream>>>(w_qkv, wqb, n8);
    n8 = TC * TC / 8;
    cvt_kernel<<<(n8 + 255) / 256, 256, 0, stream>>>(w_proj, wpb, n8);

    gemm_bt<false, true><<<dim3(TM / 128, TNQKV / 128), 256, 0, stream>>>(
        xb, wqb, (void*)qkvb, nullptr, TM, TNQKV, TC);

    transpose_v<<<dim3(TN / 64, TB * TH), 256, 0, stream>>>(qkvb, vtb);

    attn_kernel<<<768, 512, 0, stream>>>(qkvb, vtb, aob);

    gemm_bt<true, false><<<dim3(TM / 128, TC / 128), 256, 0, stream>>>(
        aob, wpb, (void*)out, b_proj, TM, TC, TC);
}